// Round 1
// baseline (353.213 us; speedup 1.0000x reference)
//
#include <hip/hip_runtime.h>
#include <stdint.h>

typedef unsigned long long u64;

#define N_ 128
#define C_ 256
#define H_ 28
#define W_ 28
#define BN_EPS_ 1e-5f

// ---------------------------------------------------------------------------
// Kernel 1: bit-pack activations. xbits layout: [n][h][w][4] u64, bit c&63 of
// word c>>6 is 1 iff x[n,c,h,w] < 0 (sign = -1).
// One thread per (n,h,w); loops over c with coalesced loads across lanes.
// ---------------------------------------------------------------------------
__global__ __launch_bounds__(256) void pack_x_kernel(const float* __restrict__ x,
                                                     u64* __restrict__ xbits) {
    int tid = blockIdx.x * blockDim.x + threadIdx.x;  // (n*H + h)*W + w
    if (tid >= N_ * H_ * W_) return;
    int w  = tid % W_;
    int hn = tid / W_;
    int h  = hn % H_;
    int n  = hn / H_;
    const float* xp = x + ((size_t)n * C_ * H_ * W_) + (size_t)h * W_ + w;
    u64 b0 = 0, b1 = 0, b2 = 0, b3 = 0;
    #pragma unroll 8
    for (int c = 0; c < 64; ++c) {
        b0 |= (u64)(xp[(size_t)(c      ) * (H_ * W_)] < 0.f) << c;
        b1 |= (u64)(xp[(size_t)(c +  64) * (H_ * W_)] < 0.f) << c;
        b2 |= (u64)(xp[(size_t)(c + 128) * (H_ * W_)] < 0.f) << c;
        b3 |= (u64)(xp[(size_t)(c + 192) * (H_ * W_)] < 0.f) << c;
    }
    u64* dst = xbits + (size_t)tid * 4;
    dst[0] = b0; dst[1] = b1; dst[2] = b2; dst[3] = b3;
}

// ---------------------------------------------------------------------------
// Kernel 2: bit-pack weights via wave ballot. wbits layout: [co][tap(9)][4].
// One wave per output word; lane j supplies channel k*64+j.
// ---------------------------------------------------------------------------
__global__ __launch_bounds__(256) void pack_w_kernel(const float* __restrict__ w,
                                                     u64* __restrict__ wbits) {
    int gid  = blockIdx.x * blockDim.x + threadIdx.x;
    int wave = gid >> 6;
    int lane = gid & 63;
    if (wave >= C_ * 9 * 4) return;
    int k    = wave & 3;
    int rest = wave >> 2;     // co*9 + tap
    int tap  = rest % 9;
    int co   = rest / 9;
    int ci   = k * 64 + lane;
    float val = w[((size_t)co * C_ + ci) * 9 + tap];
    u64 mask = __ballot(val < 0.f);
    if (lane == 0) wbits[wave] = mask;
}

// ---------------------------------------------------------------------------
// Kernel 3: binarized conv + BN + hardtanh + residual.
// Block = (n, h) pair; thread = co. Per-tap dot over 256 channels:
//   sum = 256 - 2*popc(xbits ^ wbits)   (zero-padded taps skipped).
// Input rows staged in LDS (wave-uniform broadcast reads).
// ---------------------------------------------------------------------------
__global__ __launch_bounds__(256) void conv_kernel(
    const u64* __restrict__ xbits, const u64* __restrict__ wbits,
    const float* __restrict__ x,
    const float* __restrict__ gamma, const float* __restrict__ beta,
    const float* __restrict__ mean, const float* __restrict__ var,
    float* __restrict__ out) {
    int nh = blockIdx.x;
    int h  = nh % H_;
    int n  = nh / H_;
    int co = threadIdx.x;

    float inv  = gamma[co] / sqrtf(var[co] + BN_EPS_);
    float bias = beta[co] - mean[co] * inv;

    // Per-thread weight fragments: 9 taps x 4 u64 = 72 VGPRs.
    u64 wr[9][4];
    {
        const ulonglong2* wp = (const ulonglong2*)wbits + (size_t)co * 18;
        #pragma unroll
        for (int i = 0; i < 9; ++i) {
            ulonglong2 a = wp[i * 2];
            ulonglong2 b = wp[i * 2 + 1];
            wr[i][0] = a.x; wr[i][1] = a.y; wr[i][2] = b.x; wr[i][3] = b.y;
        }
    }

    // 3 input bit-rows for this (n, h): [row][w][4 words]
    __shared__ u64 lx[3][W_][4];
    for (int i = threadIdx.x; i < 3 * W_ * 4; i += 256) {
        int k    = i & 3;
        int rest = i >> 2;
        int ww   = rest % W_;
        int r    = rest / W_;
        int ih   = h - 1 + r;
        u64 v = 0;
        if (ih >= 0 && ih < H_)
            v = xbits[(((size_t)n * H_ + ih) * W_ + ww) * 4 + k];
        lx[r][ww][k] = v;
    }
    __syncthreads();

    const float* xrow = x   + (((size_t)n * C_ + co) * H_ + h) * W_;
    float*       orow = out + (((size_t)n * C_ + co) * H_ + h) * W_;

    int dh0 = (h == 0)      ? 1 : 0;   // first valid kernel row (inclusive)
    int dh1 = (h == H_ - 1) ? 1 : 2;   // last valid kernel row (inclusive)

    for (int wq = 0; wq < W_ / 4; ++wq) {
        float4 res = ((const float4*)xrow)[wq];
        float4 o;
        float*       op = &o.x;
        const float* rp = &res.x;
        #pragma unroll
        for (int j = 0; j < 4; ++j) {
            int wpos = wq * 4 + j;
            int acc = 0;
            int nv  = 0;
            #pragma unroll
            for (int dh = 0; dh < 3; ++dh) {
                if (dh < dh0 || dh > dh1) continue;
                #pragma unroll
                for (int dw = 0; dw < 3; ++dw) {
                    int iw = wpos - 1 + dw;
                    if (iw < 0 || iw >= W_) continue;
                    nv += C_;
                    const u64* xx = lx[dh][iw];
                    const u64* wt = wr[dh * 3 + dw];
                    acc += __popcll(xx[0] ^ wt[0]) + __popcll(xx[1] ^ wt[1]) +
                           __popcll(xx[2] ^ wt[2]) + __popcll(xx[3] ^ wt[3]);
                }
            }
            float convv = (float)(nv - 2 * acc);
            float val   = convv * inv + bias;
            val = fminf(1.f, fmaxf(-1.f, val));
            op[j] = val + rp[j];
        }
        ((float4*)orow)[wq] = o;
    }
}

// ---------------------------------------------------------------------------
extern "C" void kernel_launch(void* const* d_in, const int* in_sizes, int n_in,
                              void* d_out, int out_size, void* d_ws, size_t ws_size,
                              hipStream_t stream) {
    const float* x     = (const float*)d_in[0];
    const float* w     = (const float*)d_in[1];
    const float* gamma = (const float*)d_in[2];
    const float* beta  = (const float*)d_in[3];
    const float* mean  = (const float*)d_in[4];
    const float* var   = (const float*)d_in[5];
    float* out = (float*)d_out;

    u64* xbits = (u64*)d_ws;                                 // 128*28*28*4 u64 = 3.21 MB
    u64* wbits = xbits + (size_t)N_ * H_ * W_ * 4;           // 256*9*4 u64 = 72 KB

    int npix = N_ * H_ * W_;
    pack_x_kernel<<<(npix + 255) / 256, 256, 0, stream>>>(x, xbits);
    pack_w_kernel<<<(C_ * 9 * 4 * 64) / 256, 256, 0, stream>>>(w, wbits);
    conv_kernel<<<N_ * H_, 256, 0, stream>>>(xbits, wbits, x, gamma, beta, mean, var, out);
}

// Round 2
// 325.686 us; speedup vs baseline: 1.0845x; 1.0845x over previous
//
#include <hip/hip_runtime.h>
#include <stdint.h>

typedef unsigned long long u64;

#define N_ 128
#define C_ 256
#define H_ 28
#define W_ 28
#define BN_EPS_ 1e-5f

// ---------------------------------------------------------------------------
// Kernel 1: bit-pack activations, one wave per (n, h, k-word).
// lane = channel within the 64-bit word; __ballot over lanes builds the word.
// xbits layout: [n][h][w][4] u64; bit c&63 of word c>>6 = (x[n,c,h,w] < 0).
// ---------------------------------------------------------------------------
__global__ __launch_bounds__(256) void pack_x_kernel(const float* __restrict__ x,
                                                     u64* __restrict__ xbits) {
    int gid  = blockIdx.x * blockDim.x + threadIdx.x;
    int wave = gid >> 6;            // (n*H + h)*4 + k
    int lane = gid & 63;
    int k    = wave & 3;
    int nh   = wave >> 2;           // n*H + h
    if (nh >= N_ * H_) return;
    int h = nh % H_;
    int n = nh / H_;
    int c = k * 64 + lane;
    const float* xp = x + (((size_t)n * C_ + c) * H_ + h) * W_;

    u64 my = 0;
    #pragma unroll
    for (int w = 0; w < W_; ++w) {
        u64 mask = __ballot(xp[w] < 0.f);
        if (lane == w) my = mask;
    }
    if (lane < W_) xbits[((size_t)nh * W_ + lane) * 4 + k] = my;
}

// ---------------------------------------------------------------------------
// Kernel 2: bit-pack weights via wave ballot. wbits layout: [co][tap(9)][4].
// ---------------------------------------------------------------------------
__global__ __launch_bounds__(256) void pack_w_kernel(const float* __restrict__ w,
                                                     u64* __restrict__ wbits) {
    int gid  = blockIdx.x * blockDim.x + threadIdx.x;
    int wave = gid >> 6;
    int lane = gid & 63;
    if (wave >= C_ * 9 * 4) return;
    int k    = wave & 3;
    int rest = wave >> 2;     // co*9 + tap
    int tap  = rest % 9;
    int co   = rest / 9;
    int ci   = k * 64 + lane;
    float val = w[((size_t)co * C_ + ci) * 9 + tap];
    u64 mask = __ballot(val < 0.f);
    if (lane == 0) wbits[wave] = mask;
}

// ---------------------------------------------------------------------------
// Kernel 3: binarized conv + BN + hardtanh + residual.
// Block = (n, h); thread = co. Sliding-window column pipeline along w:
// column iw contributes A(iw,0)->out(iw+1), A(iw,1)->out(iw), A(iw,2)->out(iw-1).
// Each xbits column is read from LDS exactly once per thread (wave-uniform
// broadcast, conflict-free). Outputs land in registers, then go through a
// stride-29-padded LDS transpose so the residual read + store are contiguous
// 112B-per-channel runs (coalesced).
// ---------------------------------------------------------------------------
__global__ __launch_bounds__(256) void conv_kernel(
    const u64* __restrict__ xbits, const u64* __restrict__ wbits,
    const float* __restrict__ x,
    const float* __restrict__ gamma, const float* __restrict__ beta,
    const float* __restrict__ mean, const float* __restrict__ var,
    float* __restrict__ out) {
    int nh = blockIdx.x;
    int h  = nh % H_;
    int n  = nh / H_;
    int co = threadIdx.x;

    __shared__ union {
        u64   lx[3][W_][4];       // 2688 B  (compute phase)
        float sout[C_][29];       // 29696 B (transpose phase)
    } sm;

    float inv  = gamma[co] / sqrtf(var[co] + BN_EPS_);
    float bias = beta[co] - mean[co] * inv;

    // Per-thread weight fragments: 9 taps x 4 u64 = 72 VGPRs.
    u64 wr[9][4];
    {
        const ulonglong2* wp = (const ulonglong2*)wbits + (size_t)co * 18;
        #pragma unroll
        for (int i = 0; i < 9; ++i) {
            ulonglong2 a = wp[i * 2];
            ulonglong2 b = wp[i * 2 + 1];
            wr[i][0] = a.x; wr[i][1] = a.y; wr[i][2] = b.x; wr[i][3] = b.y;
        }
    }

    // Stage 3 input bit-rows (336 u64) into LDS.
    for (int i = threadIdx.x; i < 3 * W_ * 4; i += 256) {
        int k    = i & 3;
        int rest = i >> 2;
        int ww   = rest % W_;
        int r    = rest / W_;
        int ih   = h - 1 + r;
        u64 v = 0;
        if (ih >= 0 && ih < H_)
            v = xbits[(((size_t)n * H_ + ih) * W_ + ww) * 4 + k];
        sm.lx[r][ww][k] = v;
    }
    __syncthreads();

    const bool row0 = (h > 0);
    const bool row2 = (h < H_ - 1);
    const int  nrows = 1 + (row0 ? 1 : 0) + (row2 ? 1 : 0);

    int sacc[W_];   // popcount sums per output w
    int pm = 0, pc = 0;

    for (int iw = 0; iw < W_; ++iw) {
        int a0 = 0, a1 = 0, a2 = 0;
        u64 xw0, xw1, xw2, xw3;
        #define TAPROW(r, wb)                                                  \
            xw0 = sm.lx[r][iw][0]; xw1 = sm.lx[r][iw][1];                      \
            xw2 = sm.lx[r][iw][2]; xw3 = sm.lx[r][iw][3];                      \
            a0 += __popcll(xw0 ^ wr[wb+0][0]) + __popcll(xw1 ^ wr[wb+0][1]) +  \
                  __popcll(xw2 ^ wr[wb+0][2]) + __popcll(xw3 ^ wr[wb+0][3]);   \
            a1 += __popcll(xw0 ^ wr[wb+1][0]) + __popcll(xw1 ^ wr[wb+1][1]) +  \
                  __popcll(xw2 ^ wr[wb+1][2]) + __popcll(xw3 ^ wr[wb+1][3]);   \
            a2 += __popcll(xw0 ^ wr[wb+2][0]) + __popcll(xw1 ^ wr[wb+2][1]) +  \
                  __popcll(xw2 ^ wr[wb+2][2]) + __popcll(xw3 ^ wr[wb+2][3]);
        if (row0) { TAPROW(0, 0) }
        { TAPROW(1, 3) }
        if (row2) { TAPROW(2, 6) }
        #undef TAPROW
        if (iw >= 1) sacc[iw - 1] = pm + a2;
        pm = pc + a1;
        pc = a0;
    }
    sacc[W_ - 1] = pm;

    __syncthreads();   // done with lx before overwriting as sout

    // BN + hardtanh into the LDS transpose buffer.
    #pragma unroll
    for (int w = 0; w < W_; ++w) {
        int ncols = 3 - (w == 0 ? 1 : 0) - (w == W_ - 1 ? 1 : 0);
        int nv    = C_ * nrows * ncols;
        float convv = (float)(nv - 2 * sacc[w]);
        float val   = convv * inv + bias;
        val = fminf(1.f, fmaxf(-1.f, val));
        sm.sout[co][w] = val;
    }
    __syncthreads();

    // Coalesced residual add + store: contiguous 112B per (c) run.
    const float* xplane = x   + ((size_t)n * C_ * H_ + h) * W_;   // + c*H*W + w
    float*       oplane = out + ((size_t)n * C_ * H_ + h) * W_;
    for (int i = threadIdx.x; i < C_ * W_; i += 256) {
        int c    = i / W_;
        int wpos = i - c * W_;
        size_t g = (size_t)c * (H_ * W_) + wpos;
        oplane[g] = sm.sout[c][wpos] + xplane[g];
    }
}

// ---------------------------------------------------------------------------
extern "C" void kernel_launch(void* const* d_in, const int* in_sizes, int n_in,
                              void* d_out, int out_size, void* d_ws, size_t ws_size,
                              hipStream_t stream) {
    const float* x     = (const float*)d_in[0];
    const float* w     = (const float*)d_in[1];
    const float* gamma = (const float*)d_in[2];
    const float* beta  = (const float*)d_in[3];
    const float* mean  = (const float*)d_in[4];
    const float* var   = (const float*)d_in[5];
    float* out = (float*)d_out;

    u64* xbits = (u64*)d_ws;                                 // 128*28*28*4 u64 = 3.21 MB
    u64* wbits = xbits + (size_t)N_ * H_ * W_ * 4;           // 256*9*4 u64 = 72 KB

    int pack_x_threads = N_ * H_ * 4 * 64;                   // one wave per (n,h,k)
    pack_x_kernel<<<(pack_x_threads + 255) / 256, 256, 0, stream>>>(x, xbits);
    pack_w_kernel<<<(C_ * 9 * 4 * 64) / 256, 256, 0, stream>>>(w, wbits);
    conv_kernel<<<N_ * H_, 256, 0, stream>>>(xbits, wbits, x, gamma, beta, mean, var, out);
}